// Round 12
// baseline (57174.530 us; speedup 1.0000x reference)
//
#include <hip/hip_runtime.h>

typedef unsigned short ushort;
typedef unsigned int uint32;
typedef unsigned long long ull;
typedef __attribute__((ext_vector_type(8))) short bf16x8;
typedef __attribute__((ext_vector_type(4))) float f32x4;

#define BATCH 16
#define TT 2048
#define HID 256
// whh pack entries: lane(64) x gt(4) x kt(8) x grp(2) x wv(8) x dir(2) x layer(3)
#define PACK_N (64 * 4 * 8 * 2 * 8 * 2 * 3)   // = 196608 uint4 = 3 MB

__device__ __forceinline__ ushort f2bf(float f) {
  union { float f; uint32 u; } v; v.f = f;
  uint32 r = v.u + 0x7FFFu + ((v.u >> 16) & 1u);
  return (ushort)(r >> 16);
}
__device__ __forceinline__ float bf2f(ushort u) {
  union { uint32 u; float f; } v; v.u = ((uint32)u) << 16; return v.f;
}
__device__ __forceinline__ float sigm(float x) { return 1.0f / (1.0f + __expf(-x)); }
__device__ __forceinline__ float tanh_fast(float x) { return 1.0f - 2.0f / (__expf(2.0f * x) + 1.0f); }

// extract xg value from the 4 prefetched uint4s; idx16 is compile-time
__device__ __forceinline__ float xgval(const uint4& a, const uint4& b,
                                       const uint4& c, const uint4& d, int idx16) {
  int dw = idx16 >> 1;
  uint4 q = dw < 4 ? a : dw < 8 ? b : dw < 12 ? c : d;
  uint32 w = (dw & 3) == 0 ? q.x : (dw & 3) == 1 ? q.y : (dw & 3) == 2 ? q.z : q.w;
  return bf2f((ushort)(w >> ((idx16 & 1) * 16)));
}

// ---------------- prep: xbf cast + whh packs + biases ----------------
// whh pack layout: uint4 index i = (((((layer*2+dir)*8+wv)*2+grp)*8+kt)*4+gt)*64 + lane
// holds W[gate*256 + wv*32+grp*16+(lane&15)][kt*32+(lane>>4)*8 .. +8] as bf16x8
__global__ void prep_kernel(
    const float* __restrict__ x,
    const float* __restrict__ whD_f, const float* __restrict__ whD_b,
    const float* __restrict__ wh0_f, const float* __restrict__ wh0_b,
    const float* __restrict__ wh1_f, const float* __restrict__ wh1_b,
    const float* __restrict__ dbih_f, const float* __restrict__ dbhh_f,
    const float* __restrict__ dbih_b, const float* __restrict__ dbhh_b,
    const float* __restrict__ l0bih_f, const float* __restrict__ l0bhh_f,
    const float* __restrict__ l0bih_b, const float* __restrict__ l0bhh_b,
    const float* __restrict__ l1bih_f, const float* __restrict__ l1bhh_f,
    const float* __restrict__ l1bih_b, const float* __restrict__ l1bhh_b,
    ushort* __restrict__ xbf, ushort* __restrict__ pack,
    float* __restrict__ biasA, float* __restrict__ biasB, float* __restrict__ biasC)
{
  int g = blockIdx.x * blockDim.x + threadIdx.x;
  int str = gridDim.x * blockDim.x;
  for (int i = g; i < (BATCH * TT * 256) / 4; i += str) {
    float4 v = ((const float4*)x)[i];
    ushort4 o; o.x = f2bf(v.x); o.y = f2bf(v.y); o.z = f2bf(v.z); o.w = f2bf(v.w);
    ((ushort4*)xbf)[i] = o;
  }
  // whh packs: PACK_N uint4 (round-11 bug: bound was 786432 = 4x too many ->
  // 9 MB overflow clobbered biasA/B/C. Fixed.)
  for (int i = g; i < PACK_N; i += str) {
    int idx = i;
    int lane = idx & 63; idx >>= 6;
    int gt = idx & 3; idx >>= 2;
    int kt = idx & 7; idx >>= 3;
    int grp = idx & 1; idx >>= 1;
    int wv = idx & 7; idx >>= 3;
    int dirr = idx & 1; idx >>= 1;
    int layer = idx;  // 0..2
    int sel = layer * 2 + dirr;
    const float* src = sel == 0 ? whD_f : sel == 1 ? whD_b : sel == 2 ? wh0_f :
                       sel == 3 ? wh0_b : sel == 4 ? wh1_f : wh1_b;
    int unit = wv * 32 + grp * 16 + (lane & 15);
    int k0 = kt * 32 + (lane >> 4) * 8;
    const float* p = src + (size_t)(gt * 256 + unit) * 256 + k0;
    ushort o[8];
#pragma unroll
    for (int j = 0; j < 8; ++j) o[j] = f2bf(p[j]);
    uint4 w;
    w.x = o[0] | ((uint32)o[1] << 16); w.y = o[2] | ((uint32)o[3] << 16);
    w.z = o[4] | ((uint32)o[5] << 16); w.w = o[6] | ((uint32)o[7] << 16);
    ((uint4*)pack)[i] = w;
  }
  for (int i = g; i < 2048; i += str) {
    biasA[i] = i < 1024 ? dbih_f[i] + dbhh_f[i] : dbih_b[i - 1024] + dbhh_b[i - 1024];
    biasB[i] = i < 1024 ? l0bih_f[i] + l0bhh_f[i] : l0bih_b[i - 1024] + l0bhh_b[i - 1024];
    biasC[i] = i < 1024 ? l1bih_f[i] + l1bhh_f[i] : l1bih_b[i - 1024] + l1bhh_b[i - 1024];
  }
}

// ---------------- castW: gemm weight cast (fwd|bwd concat) ----------------
__global__ void castW(const float* __restrict__ wf, const float* __restrict__ wb,
                      int K, ushort* __restrict__ out)
{
  int g = blockIdx.x * blockDim.x + threadIdx.x;
  int str = gridDim.x * blockDim.x;
  int n = 2048 * K;
  for (int i = g; i < n; i += str)
    out[i] = f2bf(i < 1024 * K ? wf[i] : wb[i - 1024 * K]);
}

// ---------------- GEMM: xp = A[32768,K] * B[2048,K]^T + bias ----------------
// xp layout: byte((dir*8+wv)*2048 + t)*4096 + (loU*4 + b>>2)*64 + ((grp*4+gate)*4 + b&3)*2
__global__ __launch_bounds__(256) void gemm_xp(
    const ushort* __restrict__ A, const ushort* __restrict__ B, int K,
    const float* __restrict__ bias, ushort* __restrict__ xp)
{
  __shared__ __align__(16) ushort lA[128 * 64];
  __shared__ __align__(16) ushort lB[128 * 64];
  const int tid = threadIdx.x;
  const int lane = tid & 63, wvm = tid >> 6;
  const int lo = lane & 15, hi = lane >> 4;
  const int wr = wvm >> 1, wc = wvm & 1;
  const int bm = blockIdx.y * 128, bn = blockIdx.x * 128;

  f32x4 acc[4][4] = {};

  const int nk = K >> 6;
  for (int kt = 0; kt < nk; ++kt) {
    uint4 ra[4], rb[4];
#pragma unroll
    for (int i = 0; i < 4; ++i) {
      int slot = i * 256 + tid;
      int r = slot >> 3, c8 = slot & 7;
      ra[i] = *(const uint4*)(A + (size_t)(bm + r) * K + kt * 64 + c8 * 8);
      rb[i] = *(const uint4*)(B + (size_t)(bn + r) * K + kt * 64 + c8 * 8);
    }
    __syncthreads();
#pragma unroll
    for (int i = 0; i < 4; ++i) {
      int slot = i * 256 + tid;
      int r = slot >> 3, c8 = slot & 7;
      int boff = r * 128 + ((c8 ^ (r & 7)) << 4);
      *(uint4*)((char*)lA + boff) = ra[i];
      *(uint4*)((char*)lB + boff) = rb[i];
    }
    __syncthreads();
#pragma unroll
    for (int kk = 0; kk < 2; ++kk) {
      bf16x8 fa[4], fb[4];
#pragma unroll
      for (int mt = 0; mt < 4; ++mt) {
        int r = wr * 64 + mt * 16 + lo;
        int c8 = kk * 4 + hi;
        fa[mt] = *(const bf16x8*)((const char*)lA + r * 128 + ((c8 ^ (r & 7)) << 4));
      }
#pragma unroll
      for (int nt = 0; nt < 4; ++nt) {
        int r = wc * 64 + nt * 16 + lo;
        int c8 = kk * 4 + hi;
        fb[nt] = *(const bf16x8*)((const char*)lB + r * 128 + ((c8 ^ (r & 7)) << 4));
      }
#pragma unroll
      for (int mt = 0; mt < 4; ++mt)
#pragma unroll
        for (int nt = 0; nt < 4; ++nt)
          acc[mt][nt] = __builtin_amdgcn_mfma_f32_16x16x32_bf16(fa[mt], fb[nt], acc[mt][nt], 0, 0, 0);
    }
  }
  // epilogue: scatter into the scan-friendly xp layout (2B stores)
#pragma unroll
  for (int nt = 0; nt < 4; ++nt) {
    int n = bn + wc * 64 + nt * 16 + lo;
    float bv = bias[n];
    int dirn = n >> 10;
    int c = n & 1023;
    int gate = c >> 8;
    int u = c & 255;
    int wvU = u >> 5, grp = (u >> 4) & 1, loU = u & 15;
    int slotbase = ((grp * 4 + gate) * 4) * 2;
#pragma unroll
    for (int mt = 0; mt < 4; ++mt) {
#pragma unroll
      for (int r = 0; r < 4; ++r) {
        int m = bm + wr * 64 + mt * 16 + hi * 4 + r;
        int b = m >> 11, t = m & 2047;
        ushort hv = f2bf(acc[mt][nt][r] + bv);
        size_t byteoff = (((size_t)(dirn * 8 + wvU) * 2048 + t) * 64 + loU * 4 + (b >> 2)) * 64
                         + slotbase + (b & 3) * 2;
        *(ushort*)((char*)xp + byteoff) = hv;
      }
    }
  }
}

// ---------------- one-CU scan: 512 thr = 8 waves, h in LDS, weights reg+stream ----
// ROLE 0: dcg (produce tagged coeff). 1: l0 (consume tagged coeff w/ spin, bf16 out).
// 2: l1 (consume coeff plain, fp32 out).
template <int ROLE>
__device__ __forceinline__ void scan_core(
    const ushort* __restrict__ xp, const ushort* __restrict__ pack,
    ull* __restrict__ coefT,
    const float* __restrict__ cwF, const float* __restrict__ cwB,
    const float* __restrict__ cbF, const float* __restrict__ cbB,
    ushort* __restrict__ outBf, float* __restrict__ outF32,
    const int dir, const int tid)
{
  const int lane = tid & 63, wv = tid >> 6;
  const int lo = lane & 15, hi = lane >> 4;

  __shared__ __align__(16) ushort hbuf[2][16][272];  // [buf][batch][unit], padded
  __shared__ float ldsCW[256];

  for (int i = tid; i < 2 * 16 * 272 / 2; i += 512) ((uint32*)hbuf)[i] = 0;
  if (ROLE == 0 && tid < 256) ldsCW[tid] = (dir ? cwB : cwF)[tid];
  const float cbias = (ROLE == 0) ? (dir ? cbB[0] : cbF[0]) : 0.f;
  __syncthreads();

  const char* pk = (const char*)pack + (size_t)dir * 524288;
  // resident weights: grp0, 16 units/wave
  bf16x8 w0[4][8];
#pragma unroll
  for (int gt = 0; gt < 4; ++gt)
#pragma unroll
    for (int kt = 0; kt < 8; ++kt)
      w0[gt][kt] = *(const bf16x8*)(pk + ((((size_t)(wv * 2 + 0) * 8 + kt) * 4 + gt) << 10) + lane * 16);
  // streamed weights base: grp1
  const char* g1b = pk + (((size_t)(wv * 2 + 1) * 8 * 4) << 10) + lane * 16;

  const char* xqb = (const char*)xp + ((size_t)(dir * 8 + wv) * 2048) * 4096 + (lo * 4 + hi) * 64;
  ull* coefD = coefT + (size_t)dir * TT * 16;

  float h0[4] = {}, h1[4] = {}, c0[4] = {}, c1[4] = {};
  uint4 xq0, xq1, xq2, xq3;
  {
    const int t0 = dir ? (TT - 1) : 0;
    const char* p = xqb + (size_t)t0 * 4096;
    xq0 = *(const uint4*)(p + 0);  xq1 = *(const uint4*)(p + 16);
    xq2 = *(const uint4*)(p + 32); xq3 = *(const uint4*)(p + 48);
  }
  ull pd0 = 0, pd1 = 0, pd2 = 0, pd3 = 0;  // coeff prefetch (ROLE 1/2)

  bf16x8 sA0, sA1, sA2, sA3, sB0, sB1, sB2, sB3;
#define LD4(B0, B1, B2, B3, KT) { \
    B0 = *(const bf16x8*)(g1b + ((KT * 4 + 0) << 10)); \
    B1 = *(const bf16x8*)(g1b + ((KT * 4 + 1) << 10)); \
    B2 = *(const bf16x8*)(g1b + ((KT * 4 + 2) << 10)); \
    B3 = *(const bf16x8*)(g1b + ((KT * 4 + 3) << 10)); }
  LD4(sA0, sA1, sA2, sA3, 0)

  const long long tdead = clock64() + 2000000000LL;

  for (int s = 0; s < TT; ++s) {
    const int rb = s & 1;
    const char* hb_r = (const char*)hbuf + rb * 8704 + lo * 544;

    // dcg: coeff[t=s-1] from h_{s-1} (in hbuf[rb]); wave 0 only
    if (ROLE == 0 && wv == 0 && s > 0) {
      const int b = lane >> 2, q = lane & 3;
      const char* hp = (const char*)hbuf + rb * 8704 + b * 544 + q * 128;
      float part = 0.f;
#pragma unroll
      for (int j = 0; j < 8; ++j) {
        bf16x8 h8 = *(const bf16x8*)(hp + j * 16);
        f32x4 cA = *(const f32x4*)(ldsCW + q * 64 + j * 8);
        f32x4 cB = *(const f32x4*)(ldsCW + q * 64 + j * 8 + 4);
#pragma unroll
        for (int e = 0; e < 4; ++e) {
          part += cA[e] * bf2f((ushort)h8[e]);
          part += cB[e] * bf2f((ushort)h8[4 + e]);
        }
      }
      part += __shfl_xor(part, 1);
      part += __shfl_xor(part, 2);
      if (q == 0) {
        uint32 pb = __float_as_uint(0.9f * sigm(part + cbias));
        __hip_atomic_store(coefD + (size_t)(s - 1) * 16 + b, (((ull)(uint32)s) << 32) | pb,
                           __ATOMIC_RELAXED, __HIP_MEMORY_SCOPE_AGENT);
      }
    }

    // ---- matvec: 8 kt tiles, g0 resident + g1 streamed (double-buffered) ----
    f32x4 a0[4] = {}, a1[4] = {};
#define MM8(J, C0, C1, C2, C3) { \
      bf16x8 af = *(const bf16x8*)(hb_r + J * 64 + hi * 16); \
      a0[0] = __builtin_amdgcn_mfma_f32_16x16x32_bf16(af, w0[0][J], a0[0], 0, 0, 0); \
      a0[1] = __builtin_amdgcn_mfma_f32_16x16x32_bf16(af, w0[1][J], a0[1], 0, 0, 0); \
      a0[2] = __builtin_amdgcn_mfma_f32_16x16x32_bf16(af, w0[2][J], a0[2], 0, 0, 0); \
      a0[3] = __builtin_amdgcn_mfma_f32_16x16x32_bf16(af, w0[3][J], a0[3], 0, 0, 0); \
      a1[0] = __builtin_amdgcn_mfma_f32_16x16x32_bf16(af, C0, a1[0], 0, 0, 0); \
      a1[1] = __builtin_amdgcn_mfma_f32_16x16x32_bf16(af, C1, a1[1], 0, 0, 0); \
      a1[2] = __builtin_amdgcn_mfma_f32_16x16x32_bf16(af, C2, a1[2], 0, 0, 0); \
      a1[3] = __builtin_amdgcn_mfma_f32_16x16x32_bf16(af, C3, a1[3], 0, 0, 0); }

    LD4(sB0, sB1, sB2, sB3, 1)  MM8(0, sA0, sA1, sA2, sA3)
    LD4(sA0, sA1, sA2, sA3, 2)  MM8(1, sB0, sB1, sB2, sB3)
    LD4(sB0, sB1, sB2, sB3, 3)  MM8(2, sA0, sA1, sA2, sA3)
    LD4(sA0, sA1, sA2, sA3, 4)  MM8(3, sB0, sB1, sB2, sB3)
    LD4(sB0, sB1, sB2, sB3, 5)  MM8(4, sA0, sA1, sA2, sA3)
    LD4(sA0, sA1, sA2, sA3, 6)  MM8(5, sB0, sB1, sB2, sB3)
    LD4(sB0, sB1, sB2, sB3, 7)  MM8(6, sA0, sA1, sA2, sA3)
    LD4(sA0, sA1, sA2, sA3, 0)  MM8(7, sB0, sB1, sB2, sB3)   // prefetch next step's kt0

    // ---- coeff for this step ----
    float co_[4] = {0.f, 0.f, 0.f, 0.f};
    if (ROLE == 1 && s > 0) {
      const uint32 want = (uint32)(s + 1);
      uint32 bad = ((uint32)(pd0 >> 32)) ^ want;
      bad |= ((uint32)(pd1 >> 32)) ^ want;
      bad |= ((uint32)(pd2 >> 32)) ^ want;
      bad |= ((uint32)(pd3 >> 32)) ^ want;
      if (!__all(bad == 0)) {
        const ull* cp = coefD + (size_t)s * 16 + hi * 4;
        while (true) {
          pd0 = __hip_atomic_load(cp + 0, __ATOMIC_RELAXED, __HIP_MEMORY_SCOPE_AGENT);
          pd1 = __hip_atomic_load(cp + 1, __ATOMIC_RELAXED, __HIP_MEMORY_SCOPE_AGENT);
          pd2 = __hip_atomic_load(cp + 2, __ATOMIC_RELAXED, __HIP_MEMORY_SCOPE_AGENT);
          pd3 = __hip_atomic_load(cp + 3, __ATOMIC_RELAXED, __HIP_MEMORY_SCOPE_AGENT);
          uint32 b2 = ((uint32)(pd0 >> 32)) ^ want;
          b2 |= ((uint32)(pd1 >> 32)) ^ want;
          b2 |= ((uint32)(pd2 >> 32)) ^ want;
          b2 |= ((uint32)(pd3 >> 32)) ^ want;
          if (__all(b2 == 0)) break;
          if (clock64() > tdead) break;
        }
      }
      co_[0] = __uint_as_float((uint32)pd0);
      co_[1] = __uint_as_float((uint32)pd1);
      co_[2] = __uint_as_float((uint32)pd2);
      co_[3] = __uint_as_float((uint32)pd3);
    } else if (ROLE == 2 && s > 0) {
      co_[0] = __uint_as_float((uint32)pd0);
      co_[1] = __uint_as_float((uint32)pd1);
      co_[2] = __uint_as_float((uint32)pd2);
      co_[3] = __uint_as_float((uint32)pd3);
    }

    // ---- gates ----
#pragma unroll
    for (int r = 0; r < 4; ++r) {
      float gi = a0[0][r] + xgval(xq0, xq1, xq2, xq3, 0 * 4 + r);
      float gf = a0[1][r] + xgval(xq0, xq1, xq2, xq3, 1 * 4 + r);
      float gg = a0[2][r] + xgval(xq0, xq1, xq2, xq3, 2 * 4 + r);
      float go = a0[3][r] + xgval(xq0, xq1, xq2, xq3, 3 * 4 + r);
      float cn = sigm(gf) * c0[r] + sigm(gi) * tanh_fast(gg);
      float hn = sigm(go) * tanh_fast(cn) + co_[r] * h0[r];
      c0[r] = cn; h0[r] = hn;
    }
#pragma unroll
    for (int r = 0; r < 4; ++r) {
      float gi = a1[0][r] + xgval(xq0, xq1, xq2, xq3, 16 + 0 * 4 + r);
      float gf = a1[1][r] + xgval(xq0, xq1, xq2, xq3, 16 + 1 * 4 + r);
      float gg = a1[2][r] + xgval(xq0, xq1, xq2, xq3, 16 + 2 * 4 + r);
      float go = a1[3][r] + xgval(xq0, xq1, xq2, xq3, 16 + 3 * 4 + r);
      float cn = sigm(gf) * c1[r] + sigm(gi) * tanh_fast(gg);
      float hn = sigm(go) * tanh_fast(cn) + co_[r] * h1[r];
      c1[r] = cn; h1[r] = hn;
    }

    // ---- publish h_s into hbuf[rb^1] ----
    {
      ushort* hw = (ushort*)((char*)hbuf + (rb ^ 1) * 8704);
      const int u0 = wv * 32 + lo, u1 = wv * 32 + 16 + lo;
#pragma unroll
      for (int r = 0; r < 4; ++r) {
        hw[(hi * 4 + r) * 272 + u0] = f2bf(h0[r]);
        hw[(hi * 4 + r) * 272 + u1] = f2bf(h1[r]);
      }
    }

    // ---- outputs ----
    const int t_nat = dir ? (TT - 1 - s) : s;
    if (ROLE == 1) {
      const int u0 = wv * 32 + lo, u1 = wv * 32 + 16 + lo;
#pragma unroll
      for (int r = 0; r < 4; ++r) {
        outBf[((size_t)(hi * 4 + r) * TT + t_nat) * 512 + dir * 256 + u0] = f2bf(h0[r]);
        outBf[((size_t)(hi * 4 + r) * TT + t_nat) * 512 + dir * 256 + u1] = f2bf(h1[r]);
      }
    } else if (ROLE == 2) {
      const int u0 = wv * 32 + lo, u1 = wv * 32 + 16 + lo;
#pragma unroll
      for (int r = 0; r < 4; ++r) {
        outF32[((size_t)(hi * 4 + r) * TT + t_nat) * 512 + dir * 256 + u0] = h0[r];
        outF32[((size_t)(hi * 4 + r) * TT + t_nat) * 512 + dir * 256 + u1] = h1[r];
      }
    }

    // ---- prefetch next step's xq (+ coeff) ----
    if (s + 1 < TT) {
      const int tn = dir ? (TT - 2 - s) : (s + 1);
      const char* p = xqb + (size_t)tn * 4096;
      xq0 = *(const uint4*)(p + 0);  xq1 = *(const uint4*)(p + 16);
      xq2 = *(const uint4*)(p + 32); xq3 = *(const uint4*)(p + 48);
      if (ROLE != 0) {
        const ull* cp = coefD + (size_t)(s + 1) * 16 + hi * 4;
        pd0 = __hip_atomic_load(cp + 0, __ATOMIC_RELAXED, __HIP_MEMORY_SCOPE_AGENT);
        pd1 = __hip_atomic_load(cp + 1, __ATOMIC_RELAXED, __HIP_MEMORY_SCOPE_AGENT);
        pd2 = __hip_atomic_load(cp + 2, __ATOMIC_RELAXED, __HIP_MEMORY_SCOPE_AGENT);
        pd3 = __hip_atomic_load(cp + 3, __ATOMIC_RELAXED, __HIP_MEMORY_SCOPE_AGENT);
      }
    }
    __syncthreads();
  }

  // dcg epilogue: coeff[TT-1] from h_{TT-1} in hbuf[0] (TT even)
  if (ROLE == 0 && wv == 0) {
    const int b = lane >> 2, q = lane & 3;
    const char* hp = (const char*)hbuf + 0 * 8704 + b * 544 + q * 128;
    float part = 0.f;
#pragma unroll
    for (int j = 0; j < 8; ++j) {
      bf16x8 h8 = *(const bf16x8*)(hp + j * 16);
      f32x4 cA = *(const f32x4*)(ldsCW + q * 64 + j * 8);
      f32x4 cB = *(const f32x4*)(ldsCW + q * 64 + j * 8 + 4);
#pragma unroll
      for (int e = 0; e < 4; ++e) {
        part += cA[e] * bf2f((ushort)h8[e]);
        part += cB[e] * bf2f((ushort)h8[4 + e]);
      }
    }
    part += __shfl_xor(part, 1);
    part += __shfl_xor(part, 2);
    if (q == 0) {
      uint32 pb = __float_as_uint(0.9f * sigm(part + cbias));
      __hip_atomic_store(coefD + (size_t)(TT - 1) * 16 + b, (((ull)(uint32)TT) << 32) | pb,
                         __ATOMIC_RELAXED, __HIP_MEMORY_SCOPE_AGENT);
    }
  }
#undef LD4
#undef MM8
}

template <int ROLE>
__global__ __launch_bounds__(512, 2) void scanK(
    const ushort* __restrict__ xp, const ushort* __restrict__ pack,
    ull* __restrict__ coefT,
    const float* __restrict__ cwF, const float* __restrict__ cwB,
    const float* __restrict__ cbF, const float* __restrict__ cbB,
    ushort* __restrict__ outBf, float* __restrict__ outF32)
{
  scan_core<ROLE>(xp, pack, coefT, cwF, cwB, cbF, cbB, outBf, outF32,
                  blockIdx.x, threadIdx.x);
}

// fused dcg + l0: 4 blocks (0,1 = dcg dirs; 2,3 = l0 dirs)
__global__ __launch_bounds__(512, 2) void fusedAB(
    const ushort* __restrict__ xpA, const ushort* __restrict__ xpB,
    const ushort* __restrict__ packD, const ushort* __restrict__ packL0,
    ull* __restrict__ coefT,
    const float* __restrict__ cwF, const float* __restrict__ cwB,
    const float* __restrict__ cbF, const float* __restrict__ cbB,
    ushort* __restrict__ xcat)
{
  const int role = blockIdx.x >> 1, dir = blockIdx.x & 1;
  if (role == 0)
    scan_core<0>(xpA, packD, coefT, cwF, cwB, cbF, cbB,
                 (ushort*)nullptr, (float*)nullptr, dir, threadIdx.x);
  else
    scan_core<1>(xpB, packL0, coefT, cwF, cwB, cbF, cbB,
                 xcat, (float*)nullptr, dir, threadIdx.x);
}

extern "C" void kernel_launch(void* const* d_in, const int* in_sizes, int n_in,
                              void* d_out, int out_size, void* d_ws, size_t ws_size,
                              hipStream_t stream)
{
  const float* x       = (const float*)d_in[0];
  const float* dWih_f  = (const float*)d_in[1];
  const float* dWhh_f  = (const float*)d_in[2];
  const float* dbih_f  = (const float*)d_in[3];
  const float* dbhh_f  = (const float*)d_in[4];
  const float* dWih_b  = (const float*)d_in[5];
  const float* dWhh_b  = (const float*)d_in[6];
  const float* dbih_b  = (const float*)d_in[7];
  const float* dbhh_b  = (const float*)d_in[8];
  const float* l0Wih_f = (const float*)d_in[9];
  const float* l0Whh_f = (const float*)d_in[10];
  const float* l0bih_f = (const float*)d_in[11];
  const float* l0bhh_f = (const float*)d_in[12];
  const float* l0Wih_b = (const float*)d_in[13];
  const float* l0Whh_b = (const float*)d_in[14];
  const float* l0bih_b = (const float*)d_in[15];
  const float* l0bhh_b = (const float*)d_in[16];
  const float* l1Wih_f = (const float*)d_in[17];
  const float* l1Whh_f = (const float*)d_in[18];
  const float* l1bih_f = (const float*)d_in[19];
  const float* l1bhh_f = (const float*)d_in[20];
  const float* l1Wih_b = (const float*)d_in[21];
  const float* l1Whh_b = (const float*)d_in[22];
  const float* l1bih_b = (const float*)d_in[23];
  const float* l1bhh_b = (const float*)d_in[24];
  const float* cw_f    = (const float*)d_in[25];
  const float* cbi_f   = (const float*)d_in[26];
  const float* cw_b    = (const float*)d_in[27];
  const float* cbi_b   = (const float*)d_in[28];

  char* ws = (char*)d_ws;
  constexpr size_t SZ_XP    = 2ull * 8 * TT * 4096;           // 128 MB per scan
  constexpr size_t OFF_XPA  = 0;
  constexpr size_t OFF_XCAT = OFF_XPA + SZ_XP;                // 32 MB; first 16 MB doubles as xbf
  constexpr size_t SZ_XCAT  = (size_t)BATCH * TT * 512 * 2;
  constexpr size_t OFF_XBF  = OFF_XCAT;                       // alias: dead before xcat written
  constexpr size_t OFF_PACK = OFF_XCAT + SZ_XCAT;
  constexpr size_t SZ_PACK  = (size_t)PACK_N * 16;            // 3 MB
  constexpr size_t OFF_WG   = OFF_PACK + SZ_PACK;
  constexpr size_t SZ_WG    = 2048ull * 512 * 2;              // 2 MB (K up to 512)
  constexpr size_t OFF_BA   = OFF_WG + SZ_WG;
  constexpr size_t OFF_BB   = OFF_BA + 8192;
  constexpr size_t OFF_BC   = OFF_BB + 8192;
  constexpr size_t OFF_CO   = OFF_BC + 8192;
  constexpr size_t SZ_CO    = 2ull * TT * 16 * 8;             // tagged coeff, 512 KB
  constexpr size_t OFF_XPB  = OFF_CO + SZ_CO;
  constexpr size_t NEED_SER = OFF_XPB;
  constexpr size_t NEED_FUS = OFF_XPB + SZ_XP;
  if (ws_size < NEED_SER) return;
  const bool fuse = (ws_size >= NEED_FUS);

  ushort* xpA   = (ushort*)(ws + OFF_XPA);
  ushort* xpB   = (ushort*)(ws + OFF_XPB);
  ushort* xcat  = (ushort*)(ws + OFF_XCAT);
  ushort* xbf   = (ushort*)(ws + OFF_XBF);
  ushort* pack  = (ushort*)(ws + OFF_PACK);
  ushort* wg    = (ushort*)(ws + OFF_WG);
  float*  biasA = (float*)(ws + OFF_BA);
  float*  biasB = (float*)(ws + OFF_BB);
  float*  biasC = (float*)(ws + OFF_BC);
  ull*    coefT = (ull*)(ws + OFF_CO);

  const ushort* packD  = pack;
  const ushort* packL0 = pack + 524288;   // +1 MB in ushorts
  const ushort* packL1 = pack + 1048576;  // +2 MB

  prep_kernel<<<512, 256, 0, stream>>>(
      x, dWhh_f, dWhh_b, l0Whh_f, l0Whh_b, l1Whh_f, l1Whh_b,
      dbih_f, dbhh_f, dbih_b, dbhh_b, l0bih_f, l0bhh_f, l0bih_b, l0bhh_b,
      l1bih_f, l1bhh_f, l1bih_b, l1bhh_b,
      xbf, pack, biasA, biasB, biasC);
  hipMemsetAsync(ws + OFF_CO, 0, SZ_CO, stream);  // clear coeff tags each replay

  if (fuse) {
    castW<<<256, 256, 0, stream>>>(dWih_f, dWih_b, 256, wg);
    gemm_xp<<<dim3(16, 256), 256, 0, stream>>>(xbf, wg, 256, biasA, xpA);
    castW<<<256, 256, 0, stream>>>(l0Wih_f, l0Wih_b, 256, wg);
    gemm_xp<<<dim3(16, 256), 256, 0, stream>>>(xbf, wg, 256, biasB, xpB);
    fusedAB<<<4, 512, 0, stream>>>(xpA, xpB, packD, packL0, coefT,
                                   cw_f, cw_b, cbi_f, cbi_b, xcat);
  } else {
    castW<<<256, 256, 0, stream>>>(dWih_f, dWih_b, 256, wg);
    gemm_xp<<<dim3(16, 256), 256, 0, stream>>>(xbf, wg, 256, biasA, xpA);
    scanK<0><<<2, 512, 0, stream>>>(xpA, packD, coefT, cw_f, cw_b, cbi_f, cbi_b,
                                    (ushort*)nullptr, (float*)nullptr);
    castW<<<256, 256, 0, stream>>>(l0Wih_f, l0Wih_b, 256, wg);
    gemm_xp<<<dim3(16, 256), 256, 0, stream>>>(xbf, wg, 256, biasB, xpA);
    scanK<1><<<2, 512, 0, stream>>>(xpA, packL0, coefT, cw_f, cw_b, cbi_f, cbi_b,
                                    xcat, (float*)nullptr);
  }
  // phase C: l1 (xpA reusable in both modes)
  castW<<<256, 256, 0, stream>>>(l1Wih_f, l1Wih_b, 512, wg);
  gemm_xp<<<dim3(16, 256), 256, 0, stream>>>(xcat, wg, 512, biasC, xpA);
  scanK<2><<<2, 512, 0, stream>>>(xpA, packL1, coefT, cw_f, cw_b, cbi_f, cbi_b,
                                  (ushort*)nullptr, (float*)d_out);
}

// Round 14
// 35326.913 us; speedup vs baseline: 1.6184x; 1.6184x over previous
//
#include <hip/hip_runtime.h>

typedef unsigned short ushort;
typedef unsigned int uint32;
typedef unsigned long long ull;
typedef __attribute__((ext_vector_type(8))) short bf16x8;
typedef __attribute__((ext_vector_type(4))) float f32x4;

#define BATCH 16
#define TT 2048
#define HID 256
// whh pack entries: lane(64) x gt(4) x kt(8) x grp(2) x wv(8) x dir(2) x layer(3)
#define PACK_N (64 * 4 * 8 * 2 * 8 * 2 * 3)   // = 196608 uint4 = 3 MB
#define HROW 264                               // hbuf row ushorts (528B: 2-way banks, free)
#define HBUFB (16 * HROW * 2)                  // bytes per h buffer = 8448

// one-CU scan shared memory: 128KB weight cache + h double-buffer + cw
// (hoisted to kernel scope so fusedAB's two scan_core instantiations share ONE copy)
struct __align__(16) ScanSh {
  uint4  lwt[8192];              // 128 KB: grp1 kt4..7, all 8 waves
  ushort hbuf[2][16][HROW];      // 16.5 KB
  float  ldsCW[256];             // 1 KB
};

__device__ __forceinline__ ushort f2bf(float f) {
  union { float f; uint32 u; } v; v.f = f;
  uint32 r = v.u + 0x7FFFu + ((v.u >> 16) & 1u);
  return (ushort)(r >> 16);
}
__device__ __forceinline__ float bf2f(ushort u) {
  union { uint32 u; float f; } v; v.u = ((uint32)u) << 16; return v.f;
}
__device__ __forceinline__ float sigm(float x) { return 1.0f / (1.0f + __expf(-x)); }
__device__ __forceinline__ float tanh_fast(float x) { return 1.0f - 2.0f / (__expf(2.0f * x) + 1.0f); }

__device__ __forceinline__ float xgval(const uint4& a, const uint4& b,
                                       const uint4& c, const uint4& d, int idx16) {
  int dw = idx16 >> 1;
  uint4 q = dw < 4 ? a : dw < 8 ? b : dw < 12 ? c : d;
  uint32 w = (dw & 3) == 0 ? q.x : (dw & 3) == 1 ? q.y : (dw & 3) == 2 ? q.z : q.w;
  return bf2f((ushort)(w >> ((idx16 & 1) * 16)));
}

// ---------------- prep: xbf cast + whh packs + biases ----------------
__global__ void prep_kernel(
    const float* __restrict__ x,
    const float* __restrict__ whD_f, const float* __restrict__ whD_b,
    const float* __restrict__ wh0_f, const float* __restrict__ wh0_b,
    const float* __restrict__ wh1_f, const float* __restrict__ wh1_b,
    const float* __restrict__ dbih_f, const float* __restrict__ dbhh_f,
    const float* __restrict__ dbih_b, const float* __restrict__ dbhh_b,
    const float* __restrict__ l0bih_f, const float* __restrict__ l0bhh_f,
    const float* __restrict__ l0bih_b, const float* __restrict__ l0bhh_b,
    const float* __restrict__ l1bih_f, const float* __restrict__ l1bhh_f,
    const float* __restrict__ l1bih_b, const float* __restrict__ l1bhh_b,
    ushort* __restrict__ xbf, ushort* __restrict__ pack,
    float* __restrict__ biasA, float* __restrict__ biasB, float* __restrict__ biasC)
{
  int g = blockIdx.x * blockDim.x + threadIdx.x;
  int str = gridDim.x * blockDim.x;
  for (int i = g; i < (BATCH * TT * 256) / 4; i += str) {
    float4 v = ((const float4*)x)[i];
    ushort4 o; o.x = f2bf(v.x); o.y = f2bf(v.y); o.z = f2bf(v.z); o.w = f2bf(v.w);
    ((ushort4*)xbf)[i] = o;
  }
  for (int i = g; i < PACK_N; i += str) {
    int idx = i;
    int lane = idx & 63; idx >>= 6;
    int gt = idx & 3; idx >>= 2;
    int kt = idx & 7; idx >>= 3;
    int grp = idx & 1; idx >>= 1;
    int wv = idx & 7; idx >>= 3;
    int dirr = idx & 1; idx >>= 1;
    int layer = idx;  // 0..2
    int sel = layer * 2 + dirr;
    const float* src = sel == 0 ? whD_f : sel == 1 ? whD_b : sel == 2 ? wh0_f :
                       sel == 3 ? wh0_b : sel == 4 ? wh1_f : wh1_b;
    int unit = wv * 32 + grp * 16 + (lane & 15);
    int k0 = kt * 32 + (lane >> 4) * 8;
    const float* p = src + (size_t)(gt * 256 + unit) * 256 + k0;
    ushort o[8];
#pragma unroll
    for (int j = 0; j < 8; ++j) o[j] = f2bf(p[j]);
    uint4 w;
    w.x = o[0] | ((uint32)o[1] << 16); w.y = o[2] | ((uint32)o[3] << 16);
    w.z = o[4] | ((uint32)o[5] << 16); w.w = o[6] | ((uint32)o[7] << 16);
    ((uint4*)pack)[i] = w;
  }
  for (int i = g; i < 2048; i += str) {
    biasA[i] = i < 1024 ? dbih_f[i] + dbhh_f[i] : dbih_b[i - 1024] + dbhh_b[i - 1024];
    biasB[i] = i < 1024 ? l0bih_f[i] + l0bhh_f[i] : l0bih_b[i - 1024] + l0bhh_b[i - 1024];
    biasC[i] = i < 1024 ? l1bih_f[i] + l1bhh_f[i] : l1bih_b[i - 1024] + l1bhh_b[i - 1024];
  }
}

// ---------------- castW ----------------
__global__ void castW(const float* __restrict__ wf, const float* __restrict__ wb,
                      int K, ushort* __restrict__ out)
{
  int g = blockIdx.x * blockDim.x + threadIdx.x;
  int str = gridDim.x * blockDim.x;
  int n = 2048 * K;
  for (int i = g; i < n; i += str)
    out[i] = f2bf(i < 1024 * K ? wf[i] : wb[i - 1024 * K]);
}

// ---------------- GEMM: xp = A[32768,K] * B[2048,K]^T + bias ----------------
__global__ __launch_bounds__(256) void gemm_xp(
    const ushort* __restrict__ A, const ushort* __restrict__ B, int K,
    const float* __restrict__ bias, ushort* __restrict__ xp)
{
  __shared__ __align__(16) ushort lA[128 * 64];
  __shared__ __align__(16) ushort lB[128 * 64];
  const int tid = threadIdx.x;
  const int lane = tid & 63, wvm = tid >> 6;
  const int lo = lane & 15, hi = lane >> 4;
  const int wr = wvm >> 1, wc = wvm & 1;
  const int bm = blockIdx.y * 128, bn = blockIdx.x * 128;

  f32x4 acc[4][4] = {};

  const int nk = K >> 6;
  for (int kt = 0; kt < nk; ++kt) {
    uint4 ra[4], rb[4];
#pragma unroll
    for (int i = 0; i < 4; ++i) {
      int slot = i * 256 + tid;
      int r = slot >> 3, c8 = slot & 7;
      ra[i] = *(const uint4*)(A + (size_t)(bm + r) * K + kt * 64 + c8 * 8);
      rb[i] = *(const uint4*)(B + (size_t)(bn + r) * K + kt * 64 + c8 * 8);
    }
    __syncthreads();
#pragma unroll
    for (int i = 0; i < 4; ++i) {
      int slot = i * 256 + tid;
      int r = slot >> 3, c8 = slot & 7;
      int boff = r * 128 + ((c8 ^ (r & 7)) << 4);
      *(uint4*)((char*)lA + boff) = ra[i];
      *(uint4*)((char*)lB + boff) = rb[i];
    }
    __syncthreads();
#pragma unroll
    for (int kk = 0; kk < 2; ++kk) {
      bf16x8 fa[4], fb[4];
#pragma unroll
      for (int mt = 0; mt < 4; ++mt) {
        int r = wr * 64 + mt * 16 + lo;
        int c8 = kk * 4 + hi;
        fa[mt] = *(const bf16x8*)((const char*)lA + r * 128 + ((c8 ^ (r & 7)) << 4));
      }
#pragma unroll
      for (int nt = 0; nt < 4; ++nt) {
        int r = wc * 64 + nt * 16 + lo;
        int c8 = kk * 4 + hi;
        fb[nt] = *(const bf16x8*)((const char*)lB + r * 128 + ((c8 ^ (r & 7)) << 4));
      }
#pragma unroll
      for (int mt = 0; mt < 4; ++mt)
#pragma unroll
        for (int nt = 0; nt < 4; ++nt)
          acc[mt][nt] = __builtin_amdgcn_mfma_f32_16x16x32_bf16(fa[mt], fb[nt], acc[mt][nt], 0, 0, 0);
    }
  }
#pragma unroll
  for (int nt = 0; nt < 4; ++nt) {
    int n = bn + wc * 64 + nt * 16 + lo;
    float bv = bias[n];
    int dirn = n >> 10;
    int c = n & 1023;
    int gate = c >> 8;
    int u = c & 255;
    int wvU = u >> 5, grp = (u >> 4) & 1, loU = u & 15;
    int slotbase = ((grp * 4 + gate) * 4) * 2;
#pragma unroll
    for (int mt = 0; mt < 4; ++mt) {
#pragma unroll
      for (int r = 0; r < 4; ++r) {
        int m = bm + wr * 64 + mt * 16 + hi * 4 + r;
        int b = m >> 11, t = m & 2047;
        ushort hv = f2bf(acc[mt][nt][r] + bv);
        size_t byteoff = (((size_t)(dirn * 8 + wvU) * 2048 + t) * 64 + loU * 4 + (b >> 2)) * 64
                         + slotbase + (b & 3) * 2;
        *(ushort*)((char*)xp + byteoff) = hv;
      }
    }
  }
}

// ---------------- one-CU scan ----------------
// 512 thr = 8 waves. h in LDS. Weights: grp0 (256KB/blk) VGPR-resident (asm-pinned),
// grp1 kt4-7 (128KB) in LDS, grp1 kt0-3 (128KB/step) streamed from L2 double-buffered.
template <int ROLE>
__device__ __forceinline__ void scan_core(
    ScanSh& sh,
    const ushort* __restrict__ xp, const ushort* __restrict__ pack,
    ull* __restrict__ coefT,
    const float* __restrict__ cwF, const float* __restrict__ cwB,
    const float* __restrict__ cbF, const float* __restrict__ cbB,
    ushort* __restrict__ outBf, float* __restrict__ outF32,
    const int dir, const int tid)
{
  const int lane = tid & 63, wv = tid >> 6;
  const int lo = lane & 15, hi = lane >> 4;

  const char* pk = (const char*)pack + (size_t)dir * 524288;

  for (int i = tid; i < 2 * 16 * HROW / 2; i += 512) ((uint32*)sh.hbuf)[i] = 0;
  // lwt[(wv*4 + kt4)*4 + gt][lane] <- pack grp1 kt 4..7
  for (int i = tid; i < 8192; i += 512) {
    int lane_ = i & 63, rest = i >> 6;          // rest = (wv*4+kt4)*4+gt
    int gt_ = rest & 3, kt4_ = (rest >> 2) & 3, wv_ = rest >> 4;
    int srcIdx = (((wv_ * 2 + 1) * 8 + 4 + kt4_) * 4 + gt_) * 64 + lane_;
    sh.lwt[i] = ((const uint4*)pk)[srcIdx];
  }
  if (ROLE == 0 && tid < 256) sh.ldsCW[tid] = (dir ? cwB : cwF)[tid];
  const float cbias = (ROLE == 0) ? (dir ? cbB[0] : cbF[0]) : 0.f;
  __syncthreads();

  // resident weights: grp0 (asm-pinned so the compiler cannot rematerialize)
  bf16x8 w0[4][8];
#pragma unroll
  for (int gt = 0; gt < 4; ++gt)
#pragma unroll
    for (int kt = 0; kt < 8; ++kt) {
      w0[gt][kt] = *(const bf16x8*)(pk + ((((size_t)(wv * 2 + 0) * 8 + kt) * 4 + gt) << 10) + lane * 16);
      asm volatile("" : "+v"(w0[gt][kt]));
    }
  const char* g1b = pk + (((size_t)(wv * 2 + 1) * 8 * 4) << 10) + lane * 16;
  const char* lwb = (const char*)sh.lwt + (((size_t)wv * 16) << 10) + lane * 16;

  const char* xqb = (const char*)xp + ((size_t)(dir * 8 + wv) * 2048) * 4096 + (lo * 4 + hi) * 64;
  ull* coefD = coefT + (size_t)dir * TT * 16;

  float h0[4] = {}, h1[4] = {}, c0[4] = {}, c1[4] = {};
  uint4 xq0, xq1, xq2, xq3;
  {
    const int t0 = dir ? (TT - 1) : 0;
    const char* p = xqb + (size_t)t0 * 4096;
    xq0 = *(const uint4*)(p + 0);  xq1 = *(const uint4*)(p + 16);
    xq2 = *(const uint4*)(p + 32); xq3 = *(const uint4*)(p + 48);
  }
  ull pd0 = 0, pd1 = 0, pd2 = 0, pd3 = 0;

  bf16x8 sA0, sA1, sA2, sA3, sB0, sB1, sB2, sB3;
#define LD4(B0, B1, B2, B3, KT) { \
    B0 = *(const bf16x8*)(g1b + ((KT * 4 + 0) << 10)); \
    B1 = *(const bf16x8*)(g1b + ((KT * 4 + 1) << 10)); \
    B2 = *(const bf16x8*)(g1b + ((KT * 4 + 2) << 10)); \
    B3 = *(const bf16x8*)(g1b + ((KT * 4 + 3) << 10)); }
  LD4(sA0, sA1, sA2, sA3, 0)
  LD4(sB0, sB1, sB2, sB3, 1)

  const long long tdead = clock64() + 2000000000LL;

  for (int s = 0; s < TT; ++s) {
    const int rb = s & 1;
    const char* hb_r = (const char*)sh.hbuf + rb * HBUFB + lo * (HROW * 2);

    if (ROLE == 0 && wv == 0 && s > 0) {
      const int b = lane >> 2, q = lane & 3;
      const char* hp = (const char*)sh.hbuf + rb * HBUFB + b * (HROW * 2) + q * 128;
      float part = 0.f;
#pragma unroll
      for (int j = 0; j < 8; ++j) {
        bf16x8 h8 = *(const bf16x8*)(hp + j * 16);
        f32x4 cA = *(const f32x4*)(sh.ldsCW + q * 64 + j * 8);
        f32x4 cB = *(const f32x4*)(sh.ldsCW + q * 64 + j * 8 + 4);
#pragma unroll
        for (int e = 0; e < 4; ++e) {
          part += cA[e] * bf2f((ushort)h8[e]);
          part += cB[e] * bf2f((ushort)h8[4 + e]);
        }
      }
      part += __shfl_xor(part, 1);
      part += __shfl_xor(part, 2);
      if (q == 0) {
        uint32 pb = __float_as_uint(0.9f * sigm(part + cbias));
        __hip_atomic_store(coefD + (size_t)(s - 1) * 16 + b, (((ull)(uint32)s) << 32) | pb,
                           __ATOMIC_RELAXED, __HIP_MEMORY_SCOPE_AGENT);
      }
    }

    f32x4 a0[4] = {}, a1[4] = {};
#define MM8S(J, C0, C1, C2, C3) { \
      bf16x8 af = *(const bf16x8*)(hb_r + J * 64 + hi * 16); \
      a0[0] = __builtin_amdgcn_mfma_f32_16x16x32_bf16(af, w0[0][J], a0[0], 0, 0, 0); \
      a0[1] = __builtin_amdgcn_mfma_f32_16x16x32_bf16(af, w0[1][J], a0[1], 0, 0, 0); \
      a0[2] = __builtin_amdgcn_mfma_f32_16x16x32_bf16(af, w0[2][J], a0[2], 0, 0, 0); \
      a0[3] = __builtin_amdgcn_mfma_f32_16x16x32_bf16(af, w0[3][J], a0[3], 0, 0, 0); \
      a1[0] = __builtin_amdgcn_mfma_f32_16x16x32_bf16(af, C0, a1[0], 0, 0, 0); \
      a1[1] = __builtin_amdgcn_mfma_f32_16x16x32_bf16(af, C1, a1[1], 0, 0, 0); \
      a1[2] = __builtin_amdgcn_mfma_f32_16x16x32_bf16(af, C2, a1[2], 0, 0, 0); \
      a1[3] = __builtin_amdgcn_mfma_f32_16x16x32_bf16(af, C3, a1[3], 0, 0, 0); }
#define MM8L(J) { \
      bf16x8 af = *(const bf16x8*)(hb_r + J * 64 + hi * 16); \
      bf16x8 l0_ = *(const bf16x8*)(lwb + (((J - 4) * 4 + 0) << 10)); \
      bf16x8 l1_ = *(const bf16x8*)(lwb + (((J - 4) * 4 + 1) << 10)); \
      bf16x8 l2_ = *(const bf16x8*)(lwb + (((J - 4) * 4 + 2) << 10)); \
      bf16x8 l3_ = *(const bf16x8*)(lwb + (((J - 4) * 4 + 3) << 10)); \
      a0[0] = __builtin_amdgcn_mfma_f32_16x16x32_bf16(af, w0[0][J], a0[0], 0, 0, 0); \
      a0[1] = __builtin_amdgcn_mfma_f32_16x16x32_bf16(af, w0[1][J], a0[1], 0, 0, 0); \
      a0[2] = __builtin_amdgcn_mfma_f32_16x16x32_bf16(af, w0[2][J], a0[2], 0, 0, 0); \
      a0[3] = __builtin_amdgcn_mfma_f32_16x16x32_bf16(af, w0[3][J], a0[3], 0, 0, 0); \
      a1[0] = __builtin_amdgcn_mfma_f32_16x16x32_bf16(af, l0_, a1[0], 0, 0, 0); \
      a1[1] = __builtin_amdgcn_mfma_f32_16x16x32_bf16(af, l1_, a1[1], 0, 0, 0); \
      a1[2] = __builtin_amdgcn_mfma_f32_16x16x32_bf16(af, l2_, a1[2], 0, 0, 0); \
      a1[3] = __builtin_amdgcn_mfma_f32_16x16x32_bf16(af, l3_, a1[3], 0, 0, 0); }

    MM8L(4) MM8L(5)
    MM8S(0, sA0, sA1, sA2, sA3)  LD4(sA0, sA1, sA2, sA3, 2)
    MM8L(6)
    MM8S(1, sB0, sB1, sB2, sB3)  LD4(sB0, sB1, sB2, sB3, 3)
    MM8L(7)
    MM8S(2, sA0, sA1, sA2, sA3)  LD4(sA0, sA1, sA2, sA3, 0)   // next-step kt0
    MM8S(3, sB0, sB1, sB2, sB3)  LD4(sB0, sB1, sB2, sB3, 1)   // next-step kt1

    // ---- coeff for this step ----
    float co_[4] = {0.f, 0.f, 0.f, 0.f};
    if (ROLE == 1 && s > 0) {
      const uint32 want = (uint32)(s + 1);
      uint32 bad = ((uint32)(pd0 >> 32)) ^ want;
      bad |= ((uint32)(pd1 >> 32)) ^ want;
      bad |= ((uint32)(pd2 >> 32)) ^ want;
      bad |= ((uint32)(pd3 >> 32)) ^ want;
      if (!__all(bad == 0)) {
        const ull* cp = coefD + (size_t)s * 16 + hi * 4;
        while (true) {
          pd0 = __hip_atomic_load(cp + 0, __ATOMIC_RELAXED, __HIP_MEMORY_SCOPE_AGENT);
          pd1 = __hip_atomic_load(cp + 1, __ATOMIC_RELAXED, __HIP_MEMORY_SCOPE_AGENT);
          pd2 = __hip_atomic_load(cp + 2, __ATOMIC_RELAXED, __HIP_MEMORY_SCOPE_AGENT);
          pd3 = __hip_atomic_load(cp + 3, __ATOMIC_RELAXED, __HIP_MEMORY_SCOPE_AGENT);
          uint32 b2 = ((uint32)(pd0 >> 32)) ^ want;
          b2 |= ((uint32)(pd1 >> 32)) ^ want;
          b2 |= ((uint32)(pd2 >> 32)) ^ want;
          b2 |= ((uint32)(pd3 >> 32)) ^ want;
          if (__all(b2 == 0)) break;
          if (clock64() > tdead) break;
        }
      }
      co_[0] = __uint_as_float((uint32)pd0);
      co_[1] = __uint_as_float((uint32)pd1);
      co_[2] = __uint_as_float((uint32)pd2);
      co_[3] = __uint_as_float((uint32)pd3);
    } else if (ROLE == 2 && s > 0) {
      co_[0] = __uint_as_float((uint32)pd0);
      co_[1] = __uint_as_float((uint32)pd1);
      co_[2] = __uint_as_float((uint32)pd2);
      co_[3] = __uint_as_float((uint32)pd3);
    }

    // ---- gates ----
#pragma unroll
    for (int r = 0; r < 4; ++r) {
      float gi = a0[0][r] + xgval(xq0, xq1, xq2, xq3, 0 * 4 + r);
      float gf = a0[1][r] + xgval(xq0, xq1, xq2, xq3, 1 * 4 + r);
      float gg = a0[2][r] + xgval(xq0, xq1, xq2, xq3, 2 * 4 + r);
      float go = a0[3][r] + xgval(xq0, xq1, xq2, xq3, 3 * 4 + r);
      float cn = sigm(gf) * c0[r] + sigm(gi) * tanh_fast(gg);
      float hn = sigm(go) * tanh_fast(cn) + co_[r] * h0[r];
      c0[r] = cn; h0[r] = hn;
    }
#pragma unroll
    for (int r = 0; r < 4; ++r) {
      float gi = a1[0][r] + xgval(xq0, xq1, xq2, xq3, 16 + 0 * 4 + r);
      float gf = a1[1][r] + xgval(xq0, xq1, xq2, xq3, 16 + 1 * 4 + r);
      float gg = a1[2][r] + xgval(xq0, xq1, xq2, xq3, 16 + 2 * 4 + r);
      float go = a1[3][r] + xgval(xq0, xq1, xq2, xq3, 16 + 3 * 4 + r);
      float cn = sigm(gf) * c1[r] + sigm(gi) * tanh_fast(gg);
      float hn = sigm(go) * tanh_fast(cn) + co_[r] * h1[r];
      c1[r] = cn; h1[r] = hn;
    }

    // ---- publish h_s into hbuf[rb^1] ----
    {
      ushort* hw = (ushort*)((char*)sh.hbuf + (rb ^ 1) * HBUFB);
      const int u0 = wv * 32 + lo, u1 = wv * 32 + 16 + lo;
#pragma unroll
      for (int r = 0; r < 4; ++r) {
        hw[(hi * 4 + r) * HROW + u0] = f2bf(h0[r]);
        hw[(hi * 4 + r) * HROW + u1] = f2bf(h1[r]);
      }
    }

    // ---- outputs ----
    const int t_nat = dir ? (TT - 1 - s) : s;
    if (ROLE == 1) {
      const int u0 = wv * 32 + lo, u1 = wv * 32 + 16 + lo;
#pragma unroll
      for (int r = 0; r < 4; ++r) {
        outBf[((size_t)(hi * 4 + r) * TT + t_nat) * 512 + dir * 256 + u0] = f2bf(h0[r]);
        outBf[((size_t)(hi * 4 + r) * TT + t_nat) * 512 + dir * 256 + u1] = f2bf(h1[r]);
      }
    } else if (ROLE == 2) {
      const int u0 = wv * 32 + lo, u1 = wv * 32 + 16 + lo;
#pragma unroll
      for (int r = 0; r < 4; ++r) {
        outF32[((size_t)(hi * 4 + r) * TT + t_nat) * 512 + dir * 256 + u0] = h0[r];
        outF32[((size_t)(hi * 4 + r) * TT + t_nat) * 512 + dir * 256 + u1] = h1[r];
      }
    }

    // ---- prefetch next step's xq (+ coeff) ----
    if (s + 1 < TT) {
      const int tn = dir ? (TT - 2 - s) : (s + 1);
      const char* p = xqb + (size_t)tn * 4096;
      xq0 = *(const uint4*)(p + 0);  xq1 = *(const uint4*)(p + 16);
      xq2 = *(const uint4*)(p + 32); xq3 = *(const uint4*)(p + 48);
      if (ROLE != 0) {
        const ull* cp = coefD + (size_t)(s + 1) * 16 + hi * 4;
        pd0 = __hip_atomic_load(cp + 0, __ATOMIC_RELAXED, __HIP_MEMORY_SCOPE_AGENT);
        pd1 = __hip_atomic_load(cp + 1, __ATOMIC_RELAXED, __HIP_MEMORY_SCOPE_AGENT);
        pd2 = __hip_atomic_load(cp + 2, __ATOMIC_RELAXED, __HIP_MEMORY_SCOPE_AGENT);
        pd3 = __hip_atomic_load(cp + 3, __ATOMIC_RELAXED, __HIP_MEMORY_SCOPE_AGENT);
      }
    }
    __syncthreads();
  }

  // dcg epilogue: coeff[TT-1] from h_{TT-1} in hbuf[0] (TT even)
  if (ROLE == 0 && wv == 0) {
    const int b = lane >> 2, q = lane & 3;
    const char* hp = (const char*)sh.hbuf + 0 * HBUFB + b * (HROW * 2) + q * 128;
    float part = 0.f;
#pragma unroll
    for (int j = 0; j < 8; ++j) {
      bf16x8 h8 = *(const bf16x8*)(hp + j * 16);
      f32x4 cA = *(const f32x4*)(sh.ldsCW + q * 64 + j * 8);
      f32x4 cB = *(const f32x4*)(sh.ldsCW + q * 64 + j * 8 + 4);
#pragma unroll
      for (int e = 0; e < 4; ++e) {
        part += cA[e] * bf2f((ushort)h8[e]);
        part += cB[e] * bf2f((ushort)h8[4 + e]);
      }
    }
    part += __shfl_xor(part, 1);
    part += __shfl_xor(part, 2);
    if (q == 0) {
      uint32 pb = __float_as_uint(0.9f * sigm(part + cbias));
      __hip_atomic_store(coefD + (size_t)(TT - 1) * 16 + b, (((ull)(uint32)TT) << 32) | pb,
                         __ATOMIC_RELAXED, __HIP_MEMORY_SCOPE_AGENT);
    }
  }
#undef LD4
#undef MM8S
#undef MM8L
}

template <int ROLE>
__global__ __launch_bounds__(512, 2) void scanK(
    const ushort* __restrict__ xp, const ushort* __restrict__ pack,
    ull* __restrict__ coefT,
    const float* __restrict__ cwF, const float* __restrict__ cwB,
    const float* __restrict__ cbF, const float* __restrict__ cbB,
    ushort* __restrict__ outBf, float* __restrict__ outF32)
{
  __shared__ ScanSh sh;
  scan_core<ROLE>(sh, xp, pack, coefT, cwF, cwB, cbF, cbB, outBf, outF32,
                  blockIdx.x, threadIdx.x);
}

// fused dcg + l0: 4 blocks (0,1 = dcg dirs; 2,3 = l0 dirs) — ONE shared alloc
__global__ __launch_bounds__(512, 2) void fusedAB(
    const ushort* __restrict__ xpA, const ushort* __restrict__ xpB,
    const ushort* __restrict__ packD, const ushort* __restrict__ packL0,
    ull* __restrict__ coefT,
    const float* __restrict__ cwF, const float* __restrict__ cwB,
    const float* __restrict__ cbF, const float* __restrict__ cbB,
    ushort* __restrict__ xcat)
{
  __shared__ ScanSh sh;
  const int role = blockIdx.x >> 1, dir = blockIdx.x & 1;
  if (role == 0)
    scan_core<0>(sh, xpA, packD, coefT, cwF, cwB, cbF, cbB,
                 (ushort*)nullptr, (float*)nullptr, dir, threadIdx.x);
  else
    scan_core<1>(sh, xpB, packL0, coefT, cwF, cwB, cbF, cbB,
                 xcat, (float*)nullptr, dir, threadIdx.x);
}

extern "C" void kernel_launch(void* const* d_in, const int* in_sizes, int n_in,
                              void* d_out, int out_size, void* d_ws, size_t ws_size,
                              hipStream_t stream)
{
  const float* x       = (const float*)d_in[0];
  const float* dWih_f  = (const float*)d_in[1];
  const float* dWhh_f  = (const float*)d_in[2];
  const float* dbih_f  = (const float*)d_in[3];
  const float* dbhh_f  = (const float*)d_in[4];
  const float* dWih_b  = (const float*)d_in[5];
  const float* dWhh_b  = (const float*)d_in[6];
  const float* dbih_b  = (const float*)d_in[7];
  const float* dbhh_b  = (const float*)d_in[8];
  const float* l0Wih_f = (const float*)d_in[9];
  const float* l0Whh_f = (const float*)d_in[10];
  const float* l0bih_f = (const float*)d_in[11];
  const float* l0bhh_f = (const float*)d_in[12];
  const float* l0Wih_b = (const float*)d_in[13];
  const float* l0Whh_b = (const float*)d_in[14];
  const float* l0bih_b = (const float*)d_in[15];
  const float* l0bhh_b = (const float*)d_in[16];
  const float* l1Wih_f = (const float*)d_in[17];
  const float* l1Whh_f = (const float*)d_in[18];
  const float* l1bih_f = (const float*)d_in[19];
  const float* l1bhh_f = (const float*)d_in[20];
  const float* l1Wih_b = (const float*)d_in[21];
  const float* l1Whh_b = (const float*)d_in[22];
  const float* l1bih_b = (const float*)d_in[23];
  const float* l1bhh_b = (const float*)d_in[24];
  const float* cw_f    = (const float*)d_in[25];
  const float* cbi_f   = (const float*)d_in[26];
  const float* cw_b    = (const float*)d_in[27];
  const float* cbi_b   = (const float*)d_in[28];

  char* ws = (char*)d_ws;
  constexpr size_t SZ_XP    = 2ull * 8 * TT * 4096;           // 128 MB per scan
  constexpr size_t OFF_XPA  = 0;
  constexpr size_t OFF_XCAT = OFF_XPA + SZ_XP;
  constexpr size_t SZ_XCAT  = (size_t)BATCH * TT * 512 * 2;   // 32 MB
  constexpr size_t OFF_XBF  = OFF_XCAT;                       // alias: dead before xcat written
  constexpr size_t OFF_PACK = OFF_XCAT + SZ_XCAT;
  constexpr size_t SZ_PACK  = (size_t)PACK_N * 16;            // 3 MB
  constexpr size_t OFF_WG   = OFF_PACK + SZ_PACK;
  constexpr size_t SZ_WG    = 2048ull * 512 * 2;              // 2 MB
  constexpr size_t OFF_BA   = OFF_WG + SZ_WG;
  constexpr size_t OFF_BB   = OFF_BA + 8192;
  constexpr size_t OFF_BC   = OFF_BB + 8192;
  constexpr size_t OFF_CO   = OFF_BC + 8192;
  constexpr size_t SZ_CO    = 2ull * TT * 16 * 8;             // tagged coeff
  constexpr size_t OFF_XPB  = OFF_CO + SZ_CO;
  constexpr size_t NEED_SER = OFF_XPB;
  constexpr size_t NEED_FUS = OFF_XPB + SZ_XP;
  if (ws_size < NEED_SER) return;
  const bool fuse = (ws_size >= NEED_FUS);

  ushort* xpA   = (ushort*)(ws + OFF_XPA);
  ushort* xpB   = (ushort*)(ws + OFF_XPB);
  ushort* xcat  = (ushort*)(ws + OFF_XCAT);
  ushort* xbf   = (ushort*)(ws + OFF_XBF);
  ushort* pack  = (ushort*)(ws + OFF_PACK);
  ushort* wg    = (ushort*)(ws + OFF_WG);
  float*  biasA = (float*)(ws + OFF_BA);
  float*  biasB = (float*)(ws + OFF_BB);
  float*  biasC = (float*)(ws + OFF_BC);
  ull*    coefT = (ull*)(ws + OFF_CO);

  const ushort* packD  = pack;
  const ushort* packL0 = pack + 524288;   // +1 MB in ushorts
  const ushort* packL1 = pack + 1048576;  // +2 MB

  prep_kernel<<<512, 256, 0, stream>>>(
      x, dWhh_f, dWhh_b, l0Whh_f, l0Whh_b, l1Whh_f, l1Whh_b,
      dbih_f, dbhh_f, dbih_b, dbhh_b, l0bih_f, l0bhh_f, l0bih_b, l0bhh_b,
      l1bih_f, l1bhh_f, l1bih_b, l1bhh_b,
      xbf, pack, biasA, biasB, biasC);
  (void)hipMemsetAsync(ws + OFF_CO, 0, SZ_CO, stream);

  if (fuse) {
    castW<<<256, 256, 0, stream>>>(dWih_f, dWih_b, 256, wg);
    gemm_xp<<<dim3(16, 256), 256, 0, stream>>>(xbf, wg, 256, biasA, xpA);
    castW<<<256, 256, 0, stream>>>(l0Wih_f, l0Wih_b, 256, wg);
    gemm_xp<<<dim3(16, 256), 256, 0, stream>>>(xbf, wg, 256, biasB, xpB);
    fusedAB<<<4, 512, 0, stream>>>(xpA, xpB, packD, packL0, coefT,
                                   cw_f, cw_b, cbi_f, cbi_b, xcat);
  } else {
    castW<<<256, 256, 0, stream>>>(dWih_f, dWih_b, 256, wg);
    gemm_xp<<<dim3(16, 256), 256, 0, stream>>>(xbf, wg, 256, biasA, xpA);
    scanK<0><<<2, 512, 0, stream>>>(xpA, packD, coefT, cw_f, cw_b, cbi_f, cbi_b,
                                    (ushort*)nullptr, (float*)nullptr);
    castW<<<256, 256, 0, stream>>>(l0Wih_f, l0Wih_b, 256, wg);
    gemm_xp<<<dim3(16, 256), 256, 0, stream>>>(xbf, wg, 256, biasB, xpA);
    scanK<1><<<2, 512, 0, stream>>>(xpA, packL0, coefT, cw_f, cw_b, cbi_f, cbi_b,
                                    xcat, (float*)nullptr);
  }
  // phase C: l1
  castW<<<256, 256, 0, stream>>>(l1Wih_f, l1Wih_b, 512, wg);
  gemm_xp<<<dim3(16, 256), 256, 0, stream>>>(xcat, wg, 512, biasC, xpA);
  scanK<2><<<2, 512, 0, stream>>>(xpA, packL1, coefT, cw_f, cw_b, cbi_f, cbi_b,
                                  (ushort*)nullptr, (float*)d_out);
}